// Round 7
// baseline (1617.960 us; speedup 1.0000x reference)
//
#include <hip/hip_runtime.h>

#define NROW 5000
#define NPAD 5056   // 79*64
#define KPAD 5120   // padded K (bits beyond 5000 are zero)
#define KW   80     // u64 words per padded row
#define KHALF 2560  // split-K=2
#define HDIM 128
#define HT_PLANE ((size_t)HDIM * KPAD)   // elements per digit plane (D2,D1,D0)
#define FXSCALE 16777216.0f              // 2^24 fixed-point scale

typedef __attribute__((ext_vector_type(8))) short bf16x8;
typedef __attribute__((ext_vector_type(4))) float f32x4;

__device__ __forceinline__ unsigned short f2bf(float f) {
    unsigned int u = __float_as_uint(f);
    unsigned int r = (u + 0x7FFFu + ((u >> 16) & 1u)) >> 16;   // RNE (exact for |int|<=256)
    return (unsigned short)r;
}

// digits of q = round(h * 2^24), q in [-2^23, 2^24]:
// D2 = q>>16 (arith, in [-128,256]), D1 = (q>>8)&255, D0 = q&255; q == D2*65536 + D1*256 + D0
__device__ __forceinline__ void fx_digits(float h, unsigned short& b2, unsigned short& b1,
                                          unsigned short& b0) {
    int q = (int)rintf(h * FXSCALE);
    b2 = f2bf((float)(q >> 16));
    b1 = f2bf((float)((q >> 8) & 255));
    b0 = f2bf((float)(q & 255));
}

// ---- prep: resolve atom indices; detect int32 vs int64 storage device-side ----
__global__ __launch_bounds__(256) void prep_atom_kernel(const unsigned int* __restrict__ atomw,
                                                        int* __restrict__ atomIdx) {
    __shared__ int s_is64;
    if (threadIdx.x == 0) {
        bool all0 = true, anynz = false;
        for (int j = 0; j < 64; ++j) {
            unsigned lo = atomw[2 * j], hi = atomw[2 * j + 1];
            all0 = all0 && (hi == 0u);
            anynz = anynz || (lo != 0u);
        }
        s_is64 = (all0 && anynz) ? 1 : 0;
    }
    __syncthreads();
    int v = blockIdx.x * 256 + threadIdx.x;
    if (v < NROW) {
        atomIdx[v] = s_is64 ? (int)atomw[2 * v] : (int)atomw[v];
    }
}

// ---------------- prep: bit-pack adjacency (A[e][r][u] -> 1 bit) ----------------
__global__ __launch_bounds__(256) void prep_pack_kernel(const int* __restrict__ adjs,
                                                        unsigned long long* __restrict__ packed) {
    const int er = blockIdx.x;            // [0, 4*NPAD)
    const int e = er / NPAD;
    const int r = er - e * NPAD;
    const int wave = threadIdx.x >> 6;
    const int lane = threadIdx.x & 63;
    const int* rowp = adjs + ((size_t)e * NROW + r) * NROW;
    unsigned long long* outp = packed + ((size_t)e * NPAD + r) * KW;
    const bool rok = (r < NROW);
    for (int c = wave; c < KW; c += 4) {
        int u = c * 64 + lane;
        int val = (rok && u < NROW) ? rowp[u] : 0;
        unsigned long long m = __ballot(val == 1);
        if (lane == 0) outp[c] = m;
    }
}

// ------- prep: h0 transposed fixed-point digit planes (hT[i][v]) from fp32 embedding -------
__global__ __launch_bounds__(256) void prep_h0T_kernel(const int* __restrict__ atomIdx,
                                                       const float* __restrict__ emb,
                                                       unsigned short* __restrict__ hTb) {
    const int i = blockIdx.y;
    const int v = blockIdx.x * 256 + threadIdx.x;   // < KPAD
    float val = 0.f;
    if (v < NROW) val = emb[(size_t)atomIdx[v] * HDIM + i];
    unsigned short b2, b1, b0;
    fx_digits(val, b2, b1, b0);
    hTb[0 * HT_PLANE + (size_t)i * KPAD + v] = b2;
    hTb[1 * HT_PLANE + (size_t)i * KPAD + v] = b1;
    hTb[2 * HT_PLANE + (size_t)i * KPAD + v] = b0;
}

// ---------------- prep: h0 fp32 row-major state ----------------
__global__ __launch_bounds__(256) void prep_h0f_kernel(const int* __restrict__ atomIdx,
                                                       const float* __restrict__ emb,
                                                       float* __restrict__ h) {
    int idx = blockIdx.x * 256 + threadIdx.x;   // < NROW*HDIM
    int v = idx >> 7, i = idx & 127;
    h[idx] = emb[(size_t)atomIdx[v] * HDIM + i];
}

// ---------------- prep: Htr[(e*128+j)*128 + i] = H[e][i][j] (fp32) ----------------
__global__ __launch_bounds__(256) void prep_Ht_kernel(const float* __restrict__ H,
                                                      float* __restrict__ Htr) {
    int idx = blockIdx.x * 256 + threadIdx.x;   // < 4*128*128
    int e = idx >> 14;
    int j = (idx >> 7) & 127;
    int i = idx & 127;
    Htr[idx] = H[((size_t)e * HDIM + i) * HDIM + j];
}

// ---- GEMM1 (EXACT): agg[e][v][j] = sum_u A[e][v][u]*h[u][j], h in 24-bit fixed point ----
// All MFMA sums are integers < 2^24 -> fp32 accumulation is exact. Planes combined in double.
__global__ __launch_bounds__(256) void gemm1_kernel(const unsigned int* __restrict__ packed32,
                                                    const unsigned short* __restrict__ hTb,
                                                    float* __restrict__ agg) {
    __shared__ unsigned short Alds[64][72];   // 64 rows x 64 k, stride 72 (pad) = 9216 B
    const int m0 = blockIdx.x * 64;
    const int e = blockIdx.y;
    const int kz = blockIdx.z;
    const int tid = threadIdx.x;
    const int lane = tid & 63;
    const int wave = tid >> 6;
    const int l15 = lane & 15;
    const int l4 = lane >> 4;
    const int colBase = wave * 32;

    f32x4 accP[3][4][2];
#pragma unroll
    for (int p = 0; p < 3; ++p)
#pragma unroll
        for (int a = 0; a < 4; ++a)
#pragma unroll
            for (int b = 0; b < 2; ++b) accP[p][a][b] = (f32x4){0.f, 0.f, 0.f, 0.f};

    const int r = tid >> 2;
    const int sub = tid & 3;
    const size_t rowbase = ((size_t)e * NPAD + (m0 + r)) * (KW * 2) + (sub >> 1);
    const int shift = (sub & 1) * 16;
    const size_t rowoff0 = (size_t)(colBase + l15) * KPAD + l4 * 8;
    const size_t rowoff1 = rowoff0 + (size_t)16 * KPAD;

    const int kend = (kz + 1) * KHALF;
    for (int k0 = kz * KHALF; k0 < kend; k0 += 64) {
        // prefetch B fragments: [nt][plane][kk/32]
        bf16x8 bfr[2][3][2];
#pragma unroll
        for (int nt = 0; nt < 2; ++nt)
#pragma unroll
            for (int pl = 0; pl < 3; ++pl) {
                const unsigned short* base =
                    hTb + (size_t)pl * HT_PLANE + (nt ? rowoff1 : rowoff0) + k0;
                bfr[nt][pl][0] = *(const bf16x8*)(base);
                bfr[nt][pl][1] = *(const bf16x8*)(base + 32);
            }

        // expand 64x64 bits -> bf16 0/1 into LDS (each thread: 16 bits -> 8 u32)
        unsigned int w32 = packed32[rowbase + (k0 >> 5)];
        unsigned int bits = (w32 >> shift) & 0xFFFFu;
        unsigned int y = bits | (bits << 15);
        unsigned int ex[8];
#pragma unroll
        for (int q = 0; q < 8; ++q)
            ex[q] = ((y >> (2 * q)) & 0x00010001u) * 0x3F80u;  // pair of bits -> pair of bf16 {0,1}
        uint4* dst = (uint4*)&Alds[r][sub * 16];
        dst[0] = make_uint4(ex[0], ex[1], ex[2], ex[3]);
        dst[1] = make_uint4(ex[4], ex[5], ex[6], ex[7]);
        __syncthreads();

#pragma unroll
        for (int kk2 = 0; kk2 < 2; ++kk2) {
#pragma unroll
            for (int mt = 0; mt < 4; ++mt) {
                bf16x8 a = *(const bf16x8*)&Alds[mt * 16 + l15][kk2 * 32 + l4 * 8];
#pragma unroll
                for (int pl = 0; pl < 3; ++pl) {
                    accP[pl][mt][0] = __builtin_amdgcn_mfma_f32_16x16x32_bf16(
                        a, bfr[0][pl][kk2], accP[pl][mt][0], 0, 0, 0);
                    accP[pl][mt][1] = __builtin_amdgcn_mfma_f32_16x16x32_bf16(
                        a, bfr[1][pl][kk2], accP[pl][mt][1], 0, 0, 0);
                }
            }
        }
        __syncthreads();
    }

    // epilogue: C layout col=lane&15, row=(lane>>4)*4+reg  [m89/m91-verified]
    float* aggz = agg + (size_t)kz * 4 * NROW * HDIM;
#pragma unroll
    for (int mt = 0; mt < 4; ++mt) {
#pragma unroll
        for (int nt = 0; nt < 2; ++nt) {
#pragma unroll
            for (int ri = 0; ri < 4; ++ri) {
                int v = m0 + mt * 16 + l4 * 4 + ri;
                if (v < NROW) {
                    int col = colBase + nt * 16 + l15;
                    double d = (double)accP[0][mt][nt][ri] * 65536.0 +
                               (double)accP[1][mt][nt][ri] * 256.0 +
                               (double)accP[2][mt][nt][ri];          // exact integer
                    float val = (float)(d * (1.0 / 16777216.0));     // one optimal rounding
                    aggz[((size_t)e * NROW + v) * HDIM + col] = val;
                }
            }
        }
    }
}

// --- GEMM2 (double acc): msg[v][i] = sum_ej Htr[ej][i]*agg[v][ej], sigmoid, fp32 out + digits ---
__global__ __launch_bounds__(256) void gemm2_kernel(const float* __restrict__ agg,
                                                    const float* __restrict__ Htr,
                                                    float* __restrict__ h,        // fp32 state, in/out
                                                    float* __restrict__ outp,     // d_out slice t (fp32)
                                                    unsigned short* __restrict__ hTb) {
    __shared__ float aggs[16][512];            // 32 KB
    __shared__ unsigned short hs[3][128][16];  // 12 KB digit transpose buffers
    const int v0 = blockIdx.x * 16;
    const int tid = threadIdx.x;
    const float* agg2 = agg + (size_t)4 * NROW * HDIM;

#pragma unroll
    for (int it = 0; it < 8; ++it) {
        int idx = it * 256 + tid;            // float4 index, 0..2047
        int vv = idx >> 7;
        int ej = (idx & 127) * 4;
        int e = ej >> 7, j = ej & 127;
        int v = v0 + vv;
        float4 val = make_float4(0.f, 0.f, 0.f, 0.f);
        if (v < NROW) {
            size_t o = ((size_t)e * NROW + v) * HDIM + j;
            float4 a = *(const float4*)&agg[o];
            float4 b = *(const float4*)&agg2[o];
            val = make_float4(a.x + b.x, a.y + b.y, a.z + b.z, a.w + b.w);
        }
        *(float4*)&aggs[vv][ej] = val;
    }
    __syncthreads();

    const int i = tid & 127;
    const int vg = tid >> 7;
    double macc[8] = {0.0, 0.0, 0.0, 0.0, 0.0, 0.0, 0.0, 0.0};
    for (int c = 0; c < 512; c += 4) {
        double w0 = (double)Htr[(size_t)(c + 0) * HDIM + i];
        double w1 = (double)Htr[(size_t)(c + 1) * HDIM + i];
        double w2 = (double)Htr[(size_t)(c + 2) * HDIM + i];
        double w3 = (double)Htr[(size_t)(c + 3) * HDIM + i];
#pragma unroll
        for (int vv = 0; vv < 8; ++vv) {
            const float4 a = *(const float4*)&aggs[vg * 8 + vv][c];  // broadcast, conflict-free
            macc[vv] += (double)a.x * w0 + (double)a.y * w1 + (double)a.z * w2 + (double)a.w * w3;
        }
    }

#pragma unroll
    for (int vv = 0; vv < 8; ++vv) {
        int v = v0 + vg * 8 + vv;
        unsigned short b2 = 0, b1 = 0, b0 = 0;
        if (v < NROW) {
            size_t o = (size_t)v * HDIM + i;
            float x = (float)((double)h[o] + macc[vv]);
            float s = 1.0f / (1.0f + expf(-x));
            outp[o] = s;                   // d_out is fp32 (reference output dtype)
            h[o] = s;                      // carry full fp32 (matches np ref)
            fx_digits(s, b2, b1, b0);
        }
        hs[0][i][vg * 8 + vv] = b2;
        hs[1][i][vg * 8 + vv] = b1;
        hs[2][i][vg * 8 + vv] = b0;
    }
    __syncthreads();
    if (tid < 128) {   // write hT[i][v0..v0+16) contiguously, all three digit planes
#pragma unroll
        for (int pl = 0; pl < 3; ++pl) {
            uint4* d = (uint4*)&hTb[(size_t)pl * HT_PLANE + (size_t)tid * KPAD + v0];
            const uint4* sp = (const uint4*)&hs[pl][tid][0];
            d[0] = sp[0];
            d[1] = sp[1];
        }
    }
}

extern "C" void kernel_launch(void* const* d_in, const int* in_sizes, int n_in,
                              void* d_out, int out_size, void* d_ws, size_t ws_size,
                              hipStream_t stream) {
    const unsigned int* atomw = (const unsigned int*)d_in[0];  // int32 OR int64 — sniffed on device
    const int* adjs = (const int*)d_in[1];                     // int32 (explicit in reference)
    // d_in[2] = max_time_steps (device scalar); reference constant T=4 hard-coded
    const float* emb = (const float*)d_in[3];                  // fp32
    const float* H = (const float*)d_in[4];                    // fp32
    float* out = (float*)d_out;                                // fp32 output

    char* ws = (char*)d_ws;
    unsigned long long* packed = (unsigned long long*)ws;            // 12,943,360 B
    size_t off = (size_t)4 * NPAD * KW * 8;
    unsigned short* hTb = (unsigned short*)(ws + off);               // 3 planes = 3,932,160 B
    off += (size_t)3 * HT_PLANE * 2;
    float* hf = (float*)(ws + off);                                  // 2,560,000 B
    off += (size_t)NROW * HDIM * 4;
    float* agg = (float*)(ws + off);                                 // 20,480,000 B
    off += (size_t)2 * 4 * NROW * HDIM * 4;
    float* Htr = (float*)(ws + off);                                 // 262,144 B
    off += (size_t)4 * HDIM * HDIM * 4;
    int* atomIdx = (int*)(ws + off);                                 // 20,000 B
    off += (size_t)NROW * 4;

    prep_atom_kernel<<<dim3((NROW + 255) / 256), 256, 0, stream>>>(atomw, atomIdx);
    prep_pack_kernel<<<dim3(4 * NPAD), 256, 0, stream>>>(adjs, packed);
    prep_h0T_kernel<<<dim3(KPAD / 256, HDIM), 256, 0, stream>>>(atomIdx, emb, hTb);
    prep_h0f_kernel<<<dim3(NROW * HDIM / 256), 256, 0, stream>>>(atomIdx, emb, hf);
    prep_Ht_kernel<<<dim3(4 * HDIM * HDIM / 256), 256, 0, stream>>>(H, Htr);

    for (int t = 0; t < 4; ++t) {
        gemm1_kernel<<<dim3(NPAD / 64, 4, 2), 256, 0, stream>>>((const unsigned int*)packed, hTb, agg);
        gemm2_kernel<<<dim3(NPAD / 16), 256, 0, stream>>>(agg, Htr, hf,
                                                          out + (size_t)t * NROW * HDIM, hTb);
    }
}

// Round 8
// 1193.155 us; speedup vs baseline: 1.3560x; 1.3560x over previous
//
#include <hip/hip_runtime.h>

#define NROW 5000
#define NPAD 5120   // 40*128 padded rows
#define KPAD 5120   // padded K (bits beyond 5000 are zero)
#define KW   80     // u64 words per padded row
#define KZ   4      // split-K
#define KQ   (KPAD / KZ)   // 1280 per split
#define HDIM 128
#define HT_PLANE ((size_t)HDIM * KPAD)   // elements per digit plane (d1, d0)
#define FXS  4194304.0f                  // 2^22 fixed-point scale
#define PART ((size_t)4 * NROW * HDIM)   // agg elements per kz part

typedef _Float16 f16x8 __attribute__((ext_vector_type(8)));
typedef float f32x4 __attribute__((ext_vector_type(4)));

__device__ __forceinline__ unsigned short f2h_int(int v) {   // exact for |v| <= 2048
    union { _Float16 h; unsigned short u; } c;
    c.h = (_Float16)(float)v;
    return c.u;
}
// q = round(h*2^22); digits base 2048: q == d1*2048 + d0, d1 in [-2048,2048], d0 in [0,2047]
__device__ __forceinline__ void fx_digits(float h, unsigned short& d1, unsigned short& d0) {
    int q = (int)rintf(h * FXS);
    d1 = f2h_int(q >> 11);
    d0 = f2h_int(q & 2047);
}

// ---- prep: resolve atom indices; detect int32 vs int64 storage device-side ----
__global__ __launch_bounds__(256) void prep_atom_kernel(const unsigned int* __restrict__ atomw,
                                                        int* __restrict__ atomIdx) {
    __shared__ int s_is64;
    if (threadIdx.x == 0) {
        bool all0 = true, anynz = false;
        for (int j = 0; j < 64; ++j) {
            unsigned lo = atomw[2 * j], hi = atomw[2 * j + 1];
            all0 = all0 && (hi == 0u);
            anynz = anynz || (lo != 0u);
        }
        s_is64 = (all0 && anynz) ? 1 : 0;
    }
    __syncthreads();
    int v = blockIdx.x * 256 + threadIdx.x;
    if (v < NROW) atomIdx[v] = s_is64 ? (int)atomw[2 * v] : (int)atomw[v];
}

// ---------------- prep: bit-pack adjacency (A[e][r][u] -> 1 bit) ----------------
__global__ __launch_bounds__(256) void prep_pack_kernel(const int* __restrict__ adjs,
                                                        unsigned long long* __restrict__ packed) {
    const int er = blockIdx.x;            // [0, 4*NPAD)
    const int e = er / NPAD;
    const int r = er - e * NPAD;
    const int wave = threadIdx.x >> 6;
    const int lane = threadIdx.x & 63;
    const int* rowp = adjs + ((size_t)e * NROW + r) * NROW;
    unsigned long long* outp = packed + ((size_t)e * NPAD + r) * KW;
    const bool rok = (r < NROW);
    for (int c = wave; c < KW; c += 4) {
        int u = c * 64 + lane;
        int val = (rok && u < NROW) ? rowp[u] : 0;
        unsigned long long m = __ballot(val == 1);
        if (lane == 0) outp[c] = m;
    }
}

// ------- prep: h0 transposed f16 digit planes (hT[i][v]) from fp32 embedding -------
__global__ __launch_bounds__(256) void prep_h0T_kernel(const int* __restrict__ atomIdx,
                                                       const float* __restrict__ emb,
                                                       unsigned short* __restrict__ hTb) {
    const int i = blockIdx.y;
    const int v = blockIdx.x * 256 + threadIdx.x;   // < KPAD
    float val = 0.f;
    if (v < NROW) val = emb[(size_t)atomIdx[v] * HDIM + i];
    unsigned short d1, d0;
    fx_digits(val, d1, d0);
    hTb[(size_t)i * KPAD + v] = d1;
    hTb[HT_PLANE + (size_t)i * KPAD + v] = d0;
}

// ---------------- prep: h0 fp32 row-major state ----------------
__global__ __launch_bounds__(256) void prep_h0f_kernel(const int* __restrict__ atomIdx,
                                                       const float* __restrict__ emb,
                                                       float* __restrict__ h) {
    int idx = blockIdx.x * 256 + threadIdx.x;   // < NROW*HDIM
    int v = idx >> 7, i = idx & 127;
    h[idx] = emb[(size_t)atomIdx[v] * HDIM + i];
}

// ---------------- prep: Htr[(e*128+j)*128 + i] = H[e][i][j] (fp32) ----------------
__global__ __launch_bounds__(256) void prep_Ht_kernel(const float* __restrict__ H,
                                                      float* __restrict__ Htr) {
    int idx = blockIdx.x * 256 + threadIdx.x;   // < 4*128*128
    int e = idx >> 14;
    int j = (idx >> 7) & 127;
    int i = idx & 127;
    Htr[idx] = H[((size_t)e * HDIM + i) * HDIM + j];
}

// ---- GEMM1 (EXACT, barrier-free, LDS-free): agg += A * h, h in 22-bit f16 digit planes ----
// Wave tile: 128 rows (mt=8) x 32 cols (nt=2); A bits expanded in-register per lane.
__global__ __launch_bounds__(256, 2) void gemm1_kernel(const uint2* __restrict__ packed2,
                                                       const unsigned short* __restrict__ hTb,
                                                       float* __restrict__ agg) {
    const int m0 = blockIdx.x * 128;
    const int e = blockIdx.y;
    const int kz = blockIdx.z;
    const int tid = threadIdx.x;
    const int lane = tid & 63;
    const int wave = tid >> 6;
    const int l15 = lane & 15;
    const int l4 = lane >> 4;
    const int colBase = wave * 32;
    const int sh = l4 * 8;

    f32x4 acc[2][8][2];
#pragma unroll
    for (int pl = 0; pl < 2; ++pl)
#pragma unroll
        for (int mt = 0; mt < 8; ++mt)
#pragma unroll
            for (int nt = 0; nt < 2; ++nt) acc[pl][mt][nt] = (f32x4){0.f, 0.f, 0.f, 0.f};

    // A row word pointers (u64 words as uint2); lane's row = m0 + mt*16 + l15
    const uint2* ap[8];
#pragma unroll
    for (int mt = 0; mt < 8; ++mt)
        ap[mt] = packed2 + ((size_t)e * NPAD + (m0 + mt * 16 + l15)) * KW;

    // B base pointers [nt][pl]; lane's col row = colBase + nt*16 + l15, k offset l4*8
    const unsigned short* bp[2][2];
#pragma unroll
    for (int nt = 0; nt < 2; ++nt)
#pragma unroll
        for (int pl = 0; pl < 2; ++pl)
            bp[nt][pl] = hTb + (size_t)pl * HT_PLANE +
                         (size_t)(colBase + nt * 16 + l15) * KPAD + l4 * 8;

    const int k0end = kz * KQ + KQ;
    for (int k0 = kz * KQ; k0 < k0end; k0 += 64) {
        const int kw = k0 >> 6;
        uint2 aw[8];
#pragma unroll
        for (int mt = 0; mt < 8; ++mt) aw[mt] = ap[mt][kw];
        f16x8 bf[2][2][2];
#pragma unroll
        for (int nt = 0; nt < 2; ++nt)
#pragma unroll
            for (int pl = 0; pl < 2; ++pl) {
                bf[nt][pl][0] = *(const f16x8*)(bp[nt][pl] + k0);
                bf[nt][pl][1] = *(const f16x8*)(bp[nt][pl] + k0 + 32);
            }
#pragma unroll
        for (int mt = 0; mt < 8; ++mt) {
#pragma unroll
            for (int kk = 0; kk < 2; ++kk) {
                unsigned int b = ((kk ? aw[mt].y : aw[mt].x) >> sh) & 0xFFu;
                unsigned int y = b | (b << 15);
                union { unsigned int u[4]; f16x8 h; } A;
#pragma unroll
                for (int q = 0; q < 4; ++q)
                    A.u[q] = ((y >> (2 * q)) & 0x00010001u) * 0x3C00u;  // bit pair -> f16 {0,1}
#pragma unroll
                for (int pl = 0; pl < 2; ++pl)
#pragma unroll
                    for (int nt = 0; nt < 2; ++nt)
                        acc[pl][mt][nt] = __builtin_amdgcn_mfma_f32_16x16x32_f16(
                            A.h, bf[nt][pl][kk], acc[pl][mt][nt], 0, 0, 0);
            }
        }
    }

    // epilogue: C layout col=lane&15, row=(lane>>4)*4+reg [m89/m91-verified]; exact digit combine
    float* aggz = agg + (size_t)kz * PART;
#pragma unroll
    for (int mt = 0; mt < 8; ++mt)
#pragma unroll
        for (int nt = 0; nt < 2; ++nt)
#pragma unroll
            for (int ri = 0; ri < 4; ++ri) {
                int v = m0 + mt * 16 + l4 * 4 + ri;
                if (v < NROW) {
                    int col = colBase + nt * 16 + l15;
                    double d = (double)acc[0][mt][nt][ri] * 2048.0 + (double)acc[1][mt][nt][ri];
                    aggz[((size_t)e * NROW + v) * HDIM + col] = (float)(d * (1.0 / 4194304.0));
                }
            }
}

// --- GEMM2 (fp32 4-bank): msg[v][i] = sum_ej Htr[ej][i]*agg[v][ej], sigmoid, fp32 out + digits ---
__global__ __launch_bounds__(256) void gemm2_kernel(const float* __restrict__ agg,
                                                    const float* __restrict__ Htr,
                                                    float* __restrict__ h,        // fp32 state, in/out
                                                    float* __restrict__ outp,     // d_out slice t (fp32)
                                                    unsigned short* __restrict__ hTb) {
    __shared__ float aggs[16][512];            // 32 KB
    __shared__ unsigned short hs[2][128][16];  // 8 KB digit transpose buffers
    const int v0 = blockIdx.x * 16;
    const int tid = threadIdx.x;

#pragma unroll
    for (int it = 0; it < 8; ++it) {
        int idx = it * 256 + tid;            // float4 index, 0..2047
        int vv = idx >> 7;
        int ej = (idx & 127) * 4;
        int e = ej >> 7, j = ej & 127;
        int v = v0 + vv;
        float4 val = make_float4(0.f, 0.f, 0.f, 0.f);
        if (v < NROW) {
            size_t o = ((size_t)e * NROW + v) * HDIM + j;
            float4 a0 = *(const float4*)&agg[o];
            float4 a1 = *(const float4*)&agg[PART + o];
            float4 a2 = *(const float4*)&agg[2 * PART + o];
            float4 a3 = *(const float4*)&agg[3 * PART + o];
            val = make_float4((a0.x + a1.x) + (a2.x + a3.x), (a0.y + a1.y) + (a2.y + a3.y),
                              (a0.z + a1.z) + (a2.z + a3.z), (a0.w + a1.w) + (a2.w + a3.w));
        }
        *(float4*)&aggs[vv][ej] = val;
    }
    __syncthreads();

    const int i = tid & 127;
    const int vg = tid >> 7;
    float m4[8][4];
#pragma unroll
    for (int vv = 0; vv < 8; ++vv)
#pragma unroll
        for (int k = 0; k < 4; ++k) m4[vv][k] = 0.f;

    for (int c = 0; c < 512; c += 4) {
        float w0 = Htr[(size_t)(c + 0) * HDIM + i];
        float w1 = Htr[(size_t)(c + 1) * HDIM + i];
        float w2 = Htr[(size_t)(c + 2) * HDIM + i];
        float w3 = Htr[(size_t)(c + 3) * HDIM + i];
#pragma unroll
        for (int vv = 0; vv < 8; ++vv) {
            const float4 a = *(const float4*)&aggs[vg * 8 + vv][c];  // broadcast, conflict-free
            m4[vv][0] += a.x * w0;
            m4[vv][1] += a.y * w1;
            m4[vv][2] += a.z * w2;
            m4[vv][3] += a.w * w3;
        }
    }

#pragma unroll
    for (int vv = 0; vv < 8; ++vv) {
        int v = v0 + vg * 8 + vv;
        unsigned short d1 = 0, d0 = 0;
        if (v < NROW) {
            size_t o = (size_t)v * HDIM + i;
            float msg = (m4[vv][0] + m4[vv][1]) + (m4[vv][2] + m4[vv][3]);
            float x = h[o] + msg;
            float s = 1.0f / (1.0f + expf(-x));
            outp[o] = s;                   // d_out is fp32 (reference output dtype)
            h[o] = s;                      // carry full fp32 (matches np ref)
            fx_digits(s, d1, d0);
        }
        hs[0][i][vg * 8 + vv] = d1;
        hs[1][i][vg * 8 + vv] = d0;
    }
    __syncthreads();
    if (tid < 128) {   // write hT[i][v0..v0+16) contiguously, both digit planes
#pragma unroll
        for (int pl = 0; pl < 2; ++pl) {
            uint4* d = (uint4*)&hTb[(size_t)pl * HT_PLANE + (size_t)tid * KPAD + v0];
            const uint4* sp = (const uint4*)&hs[pl][tid][0];
            d[0] = sp[0];
            d[1] = sp[1];
        }
    }
}

extern "C" void kernel_launch(void* const* d_in, const int* in_sizes, int n_in,
                              void* d_out, int out_size, void* d_ws, size_t ws_size,
                              hipStream_t stream) {
    const unsigned int* atomw = (const unsigned int*)d_in[0];  // int32 OR int64 — sniffed on device
    const int* adjs = (const int*)d_in[1];                     // int32
    // d_in[2] = max_time_steps; reference constant T=4 hard-coded
    const float* emb = (const float*)d_in[3];                  // fp32
    const float* H = (const float*)d_in[4];                    // fp32
    float* out = (float*)d_out;                                // fp32 output

    char* ws = (char*)d_ws;
    unsigned long long* packed = (unsigned long long*)ws;            // 4*5120*80*8 = 13,107,200 B
    size_t off = (size_t)4 * NPAD * KW * 8;
    unsigned short* hTb = (unsigned short*)(ws + off);               // 2 planes = 2,621,440 B
    off += (size_t)2 * HT_PLANE * 2;
    float* hf = (float*)(ws + off);                                  // 2,560,000 B
    off += (size_t)NROW * HDIM * 4;
    float* agg = (float*)(ws + off);                                 // 4 parts = 40,960,000 B
    off += (size_t)KZ * PART * 4;
    float* Htr = (float*)(ws + off);                                 // 262,144 B
    off += (size_t)4 * HDIM * HDIM * 4;
    int* atomIdx = (int*)(ws + off);                                 // 20,000 B
    off += (size_t)NROW * 4;

    prep_atom_kernel<<<dim3((NROW + 255) / 256), 256, 0, stream>>>(atomw, atomIdx);
    prep_pack_kernel<<<dim3(4 * NPAD), 256, 0, stream>>>(adjs, packed);
    prep_h0T_kernel<<<dim3(KPAD / 256, HDIM), 256, 0, stream>>>(atomIdx, emb, hTb);
    prep_h0f_kernel<<<dim3(NROW * HDIM / 256), 256, 0, stream>>>(atomIdx, emb, hf);
    prep_Ht_kernel<<<dim3(4 * HDIM * HDIM / 256), 256, 0, stream>>>(H, Htr);

    for (int t = 0; t < 4; ++t) {
        gemm1_kernel<<<dim3(NPAD / 128, 4, KZ), 256, 0, stream>>>((const uint2*)packed, hTb, agg);
        gemm2_kernel<<<dim3((NROW + 15) / 16), 256, 0, stream>>>(agg, Htr, hf,
                                                                 out + (size_t)t * NROW * HDIM, hTb);
    }
}

// Round 9
// 1190.269 us; speedup vs baseline: 1.3593x; 1.0024x over previous
//
#include <hip/hip_runtime.h>

#define NROW 5000
#define NPAD 5120   // 40*128 padded rows
#define KPAD 5120   // padded K (bits beyond 5000 are zero)
#define KW   80     // u64 words per padded row
#define KC   80     // 64-k chunks
#define KZ   4      // split-K
#define KCQ  20     // chunks per split
#define HDIM 128
#define FXS  4194304.0f                  // 2^22 fixed-point scale
#define PART ((size_t)4 * NROW * HDIM)   // agg elements per kz part

typedef _Float16 f16x8 __attribute__((ext_vector_type(8)));
typedef float f32x4 __attribute__((ext_vector_type(4)));

__device__ __forceinline__ unsigned short f2h_int(int v) {   // exact for |v| <= 2048
    union { _Float16 h; unsigned short u; } c;
    c.h = (_Float16)(float)v;
    return c.u;
}
// q = round(h*2^22); digits base 2048: q == d1*2048 + d0, d1 in [-1024,2048], d0 in [0,2047]
__device__ __forceinline__ void fx_digits(float h, unsigned short& d1, unsigned short& d0) {
    int q = (int)rintf(h * FXS);
    d1 = f2h_int(q >> 11);
    d0 = f2h_int(q & 2047);
}

// k-tiled digit-plane layout: element(pl, kc, i, kin) = ((pl*KC + kc)*HDIM + i)*64 + kin
__device__ __forceinline__ size_t ht_idx(int pl, int kc, int i, int kin) {
    return (((size_t)pl * KC + kc) * HDIM + i) * 64 + kin;
}

// ---- prep: resolve atom indices; detect int32 vs int64 storage device-side ----
__global__ __launch_bounds__(256) void prep_atom_kernel(const unsigned int* __restrict__ atomw,
                                                        int* __restrict__ atomIdx) {
    __shared__ int s_is64;
    if (threadIdx.x == 0) {
        bool all0 = true, anynz = false;
        for (int j = 0; j < 64; ++j) {
            unsigned lo = atomw[2 * j], hi = atomw[2 * j + 1];
            all0 = all0 && (hi == 0u);
            anynz = anynz || (lo != 0u);
        }
        s_is64 = (all0 && anynz) ? 1 : 0;
    }
    __syncthreads();
    int v = blockIdx.x * 256 + threadIdx.x;
    if (v < NROW) atomIdx[v] = s_is64 ? (int)atomw[2 * v] : (int)atomw[v];
}

// ---------------- prep: bit-pack adjacency (A[e][r][u] -> 1 bit) ----------------
__global__ __launch_bounds__(256) void prep_pack_kernel(const int* __restrict__ adjs,
                                                        unsigned long long* __restrict__ packed) {
    const int er = blockIdx.x;            // [0, 4*NPAD)
    const int e = er / NPAD;
    const int r = er - e * NPAD;
    const int wave = threadIdx.x >> 6;
    const int lane = threadIdx.x & 63;
    const int* rowp = adjs + ((size_t)e * NROW + r) * NROW;
    unsigned long long* outp = packed + ((size_t)e * NPAD + r) * KW;
    const bool rok = (r < NROW);
    for (int c = wave; c < KW; c += 4) {
        int u = c * 64 + lane;
        int val = (rok && u < NROW) ? rowp[u] : 0;
        unsigned long long m = __ballot(val == 1);
        if (lane == 0) outp[c] = m;
    }
}

// ------- prep: h0 -> k-tiled f16 digit planes from fp32 embedding -------
__global__ __launch_bounds__(256) void prep_h0T_kernel(const int* __restrict__ atomIdx,
                                                       const float* __restrict__ emb,
                                                       unsigned short* __restrict__ hTt) {
    const int i = blockIdx.y;
    const int v = blockIdx.x * 256 + threadIdx.x;   // < KPAD
    float val = 0.f;
    if (v < NROW) val = emb[(size_t)atomIdx[v] * HDIM + i];
    unsigned short d1, d0;
    fx_digits(val, d1, d0);
    hTt[ht_idx(0, v >> 6, i, v & 63)] = d1;
    hTt[ht_idx(1, v >> 6, i, v & 63)] = d0;
}

// ---------------- prep: h0 fp32 row-major state ----------------
__global__ __launch_bounds__(256) void prep_h0f_kernel(const int* __restrict__ atomIdx,
                                                       const float* __restrict__ emb,
                                                       float* __restrict__ h) {
    int idx = blockIdx.x * 256 + threadIdx.x;   // < NROW*HDIM
    int v = idx >> 7, i = idx & 127;
    h[idx] = emb[(size_t)atomIdx[v] * HDIM + i];
}

// ---------------- prep: Htr[(e*128+j)*128 + i] = H[e][i][j] (fp32) ----------------
__global__ __launch_bounds__(256) void prep_Ht_kernel(const float* __restrict__ H,
                                                      float* __restrict__ Htr) {
    int idx = blockIdx.x * 256 + threadIdx.x;   // < 4*128*128
    int e = idx >> 14;
    int j = (idx >> 7) & 127;
    int i = idx & 127;
    Htr[idx] = H[((size_t)e * HDIM + i) * HDIM + j];
}

__device__ __forceinline__ void loadB(const _Float16* __restrict__ bbase, int kc, int col0,
                                      int sh, f16x8 (&dst)[2][2][2]) {
#pragma unroll
    for (int pl = 0; pl < 2; ++pl)
#pragma unroll
        for (int nt = 0; nt < 2; ++nt) {
            const _Float16* p =
                bbase + (((size_t)pl * KC + kc) * HDIM + col0 + nt * 16) * 64 + sh;
            dst[pl][nt][0] = *(const f16x8*)p;          // contiguous 2KB tile per instr
            dst[pl][nt][1] = *(const f16x8*)(p + 32);
        }
}

// ---- GEMM1 (EXACT, barrier-free, LDS-free): agg += A * h, h in 22-bit f16 digit planes ----
// Wave tile 128 rows x 32 cols; A bits expanded in-register; B register-double-buffered.
__global__ __launch_bounds__(256, 2) void gemm1_kernel(const uint2* __restrict__ packed2,
                                                       const unsigned short* __restrict__ hTt,
                                                       float* __restrict__ agg) {
    const int m0 = blockIdx.x * 128;
    const int e = blockIdx.y;
    const int kz = blockIdx.z;
    const int tid = threadIdx.x;
    const int lane = tid & 63;
    const int wave = tid >> 6;
    const int l15 = lane & 15;
    const int l4 = lane >> 4;
    const int colBase = wave * 32;
    const int sh = l4 * 8;
    const int col0 = colBase + l15;

    f32x4 acc[2][8][2];
#pragma unroll
    for (int pl = 0; pl < 2; ++pl)
#pragma unroll
        for (int mt = 0; mt < 8; ++mt)
#pragma unroll
            for (int nt = 0; nt < 2; ++nt) acc[pl][mt][nt] = (f32x4){0.f, 0.f, 0.f, 0.f};

    const uint2* ap[8];
#pragma unroll
    for (int mt = 0; mt < 8; ++mt)
        ap[mt] = packed2 + ((size_t)e * NPAD + (m0 + mt * 16 + l15)) * KW;

    const _Float16* bbase = (const _Float16*)hTt;
    const int kc0 = kz * KCQ;

    f16x8 bf[2][2][2];
    loadB(bbase, kc0, col0, sh, bf);

    for (int kc = kc0; kc < kc0 + KCQ; ++kc) {
        uint2 aw[8];
#pragma unroll
        for (int mt = 0; mt < 8; ++mt) aw[mt] = ap[mt][kc];
        const int kn = (kc + 1 < kc0 + KCQ) ? (kc + 1) : kc;
        f16x8 bfn[2][2][2];
        loadB(bbase, kn, col0, sh, bfn);   // prefetch next chunk (in-flight over MFMAs)

#pragma unroll
        for (int mt = 0; mt < 8; ++mt) {
#pragma unroll
            for (int kk = 0; kk < 2; ++kk) {
                unsigned int b = ((kk ? aw[mt].y : aw[mt].x) >> sh) & 0xFFu;
                unsigned int y = b | (b << 15);
                union { unsigned int u[4]; f16x8 h; } A;
#pragma unroll
                for (int q = 0; q < 4; ++q)
                    A.u[q] = ((y >> (2 * q)) & 0x00010001u) * 0x3C00u;  // bit pair -> f16 {0,1}
#pragma unroll
                for (int pl = 0; pl < 2; ++pl)
#pragma unroll
                    for (int nt = 0; nt < 2; ++nt)
                        acc[pl][mt][nt] = __builtin_amdgcn_mfma_f32_16x16x32_f16(
                            A.h, bf[pl][nt][kk], acc[pl][mt][nt], 0, 0, 0);
            }
        }
#pragma unroll
        for (int pl = 0; pl < 2; ++pl)
#pragma unroll
            for (int nt = 0; nt < 2; ++nt) {
                bf[pl][nt][0] = bfn[pl][nt][0];
                bf[pl][nt][1] = bfn[pl][nt][1];
            }
    }

    // epilogue: C layout col=lane&15, row=(lane>>4)*4+reg [m89/m91-verified]; exact digit combine
    float* aggz = agg + (size_t)kz * PART;
#pragma unroll
    for (int mt = 0; mt < 8; ++mt)
#pragma unroll
        for (int nt = 0; nt < 2; ++nt)
#pragma unroll
            for (int ri = 0; ri < 4; ++ri) {
                int v = m0 + mt * 16 + l4 * 4 + ri;
                if (v < NROW) {
                    int col = colBase + nt * 16 + l15;
                    double d = (double)acc[0][mt][nt][ri] * 2048.0 + (double)acc[1][mt][nt][ri];
                    aggz[((size_t)e * NROW + v) * HDIM + col] = (float)(d * (1.0 / 4194304.0));
                }
            }
}

// --- GEMM2 (fp32 4-bank): msg[v][i] = sum_ej Htr[ej][i]*agg[v][ej], sigmoid, fp32 out + digits ---
__global__ __launch_bounds__(256) void gemm2_kernel(const float* __restrict__ agg,
                                                    const float* __restrict__ Htr,
                                                    float* __restrict__ h,        // fp32 state, in/out
                                                    float* __restrict__ outp,     // d_out slice t (fp32)
                                                    unsigned short* __restrict__ hTt) {
    __shared__ float aggs[16][512];            // 32 KB
    __shared__ unsigned short hs[2][128][16];  // 8 KB digit transpose buffers
    const int v0 = blockIdx.x * 16;
    const int tid = threadIdx.x;

#pragma unroll
    for (int it = 0; it < 8; ++it) {
        int idx = it * 256 + tid;            // float4 index, 0..2047
        int vv = idx >> 7;
        int ej = (idx & 127) * 4;
        int e = ej >> 7, j = ej & 127;
        int v = v0 + vv;
        float4 val = make_float4(0.f, 0.f, 0.f, 0.f);
        if (v < NROW) {
            size_t o = ((size_t)e * NROW + v) * HDIM + j;
            float4 a0 = *(const float4*)&agg[o];
            float4 a1 = *(const float4*)&agg[PART + o];
            float4 a2 = *(const float4*)&agg[2 * PART + o];
            float4 a3 = *(const float4*)&agg[3 * PART + o];
            val = make_float4((a0.x + a1.x) + (a2.x + a3.x), (a0.y + a1.y) + (a2.y + a3.y),
                              (a0.z + a1.z) + (a2.z + a3.z), (a0.w + a1.w) + (a2.w + a3.w));
        }
        *(float4*)&aggs[vv][ej] = val;
    }
    __syncthreads();

    const int i = tid & 127;
    const int vg = tid >> 7;
    float m4[8][4];
#pragma unroll
    for (int vv = 0; vv < 8; ++vv)
#pragma unroll
        for (int k = 0; k < 4; ++k) m4[vv][k] = 0.f;

    for (int c = 0; c < 512; c += 4) {
        float w0 = Htr[(size_t)(c + 0) * HDIM + i];
        float w1 = Htr[(size_t)(c + 1) * HDIM + i];
        float w2 = Htr[(size_t)(c + 2) * HDIM + i];
        float w3 = Htr[(size_t)(c + 3) * HDIM + i];
#pragma unroll
        for (int vv = 0; vv < 8; ++vv) {
            const float4 a = *(const float4*)&aggs[vg * 8 + vv][c];  // broadcast, conflict-free
            m4[vv][0] += a.x * w0;
            m4[vv][1] += a.y * w1;
            m4[vv][2] += a.z * w2;
            m4[vv][3] += a.w * w3;
        }
    }

#pragma unroll
    for (int vv = 0; vv < 8; ++vv) {
        int v = v0 + vg * 8 + vv;
        unsigned short d1 = 0, d0 = 0;
        if (v < NROW) {
            size_t o = (size_t)v * HDIM + i;
            float msg = (m4[vv][0] + m4[vv][1]) + (m4[vv][2] + m4[vv][3]);
            float x = h[o] + msg;
            float s = 1.0f / (1.0f + expf(-x));
            outp[o] = s;                   // d_out is fp32 (reference output dtype)
            h[o] = s;                      // carry full fp32 (matches np ref)
            fx_digits(s, d1, d0);
        }
        hs[0][i][vg * 8 + vv] = d1;
        hs[1][i][vg * 8 + vv] = d0;
    }
    __syncthreads();
    if (tid < 128) {   // write 16 contiguous kin-entries in k-tiled layout, both planes
#pragma unroll
        for (int pl = 0; pl < 2; ++pl) {
            uint4* d = (uint4*)&hTt[ht_idx(pl, v0 >> 6, tid, v0 & 63)];
            const uint4* sp = (const uint4*)&hs[pl][tid][0];
            d[0] = sp[0];
            d[1] = sp[1];
        }
    }
}

extern "C" void kernel_launch(void* const* d_in, const int* in_sizes, int n_in,
                              void* d_out, int out_size, void* d_ws, size_t ws_size,
                              hipStream_t stream) {
    const unsigned int* atomw = (const unsigned int*)d_in[0];  // int32 OR int64 — sniffed on device
    const int* adjs = (const int*)d_in[1];                     // int32
    // d_in[2] = max_time_steps; reference constant T=4 hard-coded
    const float* emb = (const float*)d_in[3];                  // fp32
    const float* H = (const float*)d_in[4];                    // fp32
    float* out = (float*)d_out;                                // fp32 output

    char* ws = (char*)d_ws;
    unsigned long long* packed = (unsigned long long*)ws;            // 13,107,200 B
    size_t off = (size_t)4 * NPAD * KW * 8;
    unsigned short* hTt = (unsigned short*)(ws + off);               // 2 planes k-tiled = 2,621,440 B
    off += (size_t)2 * KC * HDIM * 64 * 2;
    float* hf = (float*)(ws + off);                                  // 2,560,000 B
    off += (size_t)NROW * HDIM * 4;
    float* agg = (float*)(ws + off);                                 // 4 parts = 40,960,000 B
    off += (size_t)KZ * PART * 4;
    float* Htr = (float*)(ws + off);                                 // 262,144 B
    off += (size_t)4 * HDIM * HDIM * 4;
    int* atomIdx = (int*)(ws + off);                                 // 20,000 B
    off += (size_t)NROW * 4;

    prep_atom_kernel<<<dim3((NROW + 255) / 256), 256, 0, stream>>>(atomw, atomIdx);
    prep_pack_kernel<<<dim3(4 * NPAD), 256, 0, stream>>>(adjs, packed);
    prep_h0T_kernel<<<dim3(KPAD / 256, HDIM), 256, 0, stream>>>(atomIdx, emb, hTt);
    prep_h0f_kernel<<<dim3(NROW * HDIM / 256), 256, 0, stream>>>(atomIdx, emb, hf);
    prep_Ht_kernel<<<dim3(4 * HDIM * HDIM / 256), 256, 0, stream>>>(H, Htr);

    for (int t = 0; t < 4; ++t) {
        gemm1_kernel<<<dim3(NPAD / 128, 4, KZ), 256, 0, stream>>>((const uint2*)packed, hTt, agg);
        gemm2_kernel<<<dim3((NROW + 15) / 16), 256, 0, stream>>>(agg, Htr, hf,
                                                                 out + (size_t)t * NROW * HDIM, hTt);
    }
}